// Round 14
// baseline (333.252 us; speedup 1.0000x reference)
//
#include <hip/hip_runtime.h>
#include <hip/hip_bf16.h>

#define CDIM   64
#define HWDIM  4096
#define NCODES 1024
#define NELEM  8388608   // 32*64*64*64 = N*C
#define NBLOCK 256       // vq_main grid: one block per CU, 512 rows each
#define NPART  (NBLOCK * 16)
#define LDSSZ  (131072 + 16 * 68 * 4)   // 128 KB codebook + padded bias

typedef short bf16x8 __attribute__((ext_vector_type(8)));
typedef float f32x4  __attribute__((ext_vector_type(4)));

__device__ __forceinline__ unsigned short f2bf(float f) {
    union { float f; unsigned u; } v; v.f = f;
    unsigned r = v.u + 0x7fffu + ((v.u >> 16) & 1u);   // round-to-nearest-even
    return (unsigned short)(r >> 16);
}
__device__ __forceinline__ unsigned asu(float f) {
    union { float f; unsigned u; } v; v.f = f; return v.u;
}
__device__ __forceinline__ float asf(unsigned u) {
    union { unsigned u; float f; } v; v.u = u; return v.f;
}

// ====================== real kernel (R13, unchanged) ======================
__global__ __launch_bounds__(1024)
void vq_main(const float* __restrict__ z,
             const float* __restrict__ E,
             float* __restrict__ out,
             float* __restrict__ partial) {
    extern __shared__ char smem[];
    unsigned short* sEb = (unsigned short*)smem;           // 128 KB swizzled
    float (*sBiasT)[68] = (float(*)[68])(smem + 131072);   // [16][68] padded

    const int lane = threadIdx.x & 63;
    const int wave = threadIdx.x >> 6;   // 0..15
    const int lrow = lane & 15;
    const int lgrp = lane >> 4;

    const int n0 = blockIdx.x * 512 + wave * 32;
    const int b  = n0 >> 12;
    const int hw = n0 & 4095;
    const float* zb   = z   + (size_t)b * (CDIM * HWDIM);
    float*       outb = out + (size_t)b * (CDIM * HWDIM);

    {   // fused prep+stage: thread t owns code t
        const int t = threadIdx.x;
        const float4* ev = (const float4*)(E + t * CDIM);
        float s = 0.f;
        #pragma unroll
        for (int k = 0; k < 8; ++k) {
            float4 va = ev[2 * k], vb = ev[2 * k + 1];
            s = fmaf(va.x, va.x, s); s = fmaf(va.y, va.y, s);
            s = fmaf(va.z, va.z, s); s = fmaf(va.w, va.w, s);
            s = fmaf(vb.x, vb.x, s); s = fmaf(vb.y, vb.y, s);
            s = fmaf(vb.z, vb.z, s); s = fmaf(vb.w, vb.w, s);
            bf16x8 w;
            w[0] = (short)f2bf(va.x); w[1] = (short)f2bf(va.y);
            w[2] = (short)f2bf(va.z); w[3] = (short)f2bf(va.w);
            w[4] = (short)f2bf(vb.x); w[5] = (short)f2bf(vb.y);
            w[6] = (short)f2bf(vb.z); w[7] = (short)f2bf(vb.w);
            *(bf16x8*)((char*)sEb + t * 128 + ((k ^ (t & 7)) << 4)) = w;
        }
        sBiasT[t & 15][t >> 4] = -0.5f * s;
    }

    float szz = 0.f;
    bf16x8 afrag[2][2];
    #pragma unroll
    for (int t = 0; t < 2; ++t)
        #pragma unroll
        for (int s = 0; s < 2; ++s)
            #pragma unroll
            for (int j = 0; j < 8; ++j) {
                int c = 32 * s + 8 * lgrp + j;
                float v = zb[c * HWDIM + hw + t * 16 + lrow];
                szz = fmaf(v, v, szz);
                afrag[t][s][j] = (short)f2bf(v);
            }

    float run[2][4];
    #pragma unroll
    for (int t = 0; t < 2; ++t)
        #pragma unroll
        for (int r = 0; r < 4; ++r) run[t][r] = -3.0e38f;

    __syncthreads();

    const int s0byte = (lgrp ^ (lrow & 7)) << 4;
    const char* pa = (const char*)sEb + lrow * 128 + s0byte;
    const char* pb = (const char*)sEb + lrow * 128 + (s0byte ^ 64);
    const float* pbias = &sBiasT[lrow][0];
    unsigned codev = (unsigned)lrow;

    for (int ch = 0; ch < 8; ++ch) {
        f32x4 bq0 = *(const f32x4*)(pbias);
        f32x4 bq1 = *(const f32x4*)(pbias + 4);
        #pragma unroll
        for (int j = 0; j < 8; ++j) {
            bf16x8 b0 = *(const bf16x8*)(pa + j * 2048);
            bf16x8 b1 = *(const bf16x8*)(pb + j * 2048);
            const float bv = (j < 4) ? bq0[j] : bq1[j - 4];
            f32x4 ci = {bv, bv, bv, bv};
            f32x4 a0 = __builtin_amdgcn_mfma_f32_16x16x32_bf16(afrag[0][0], b0, ci, 0, 0, 0);
            a0 = __builtin_amdgcn_mfma_f32_16x16x32_bf16(afrag[0][1], b1, a0, 0, 0, 0);
            f32x4 a1 = __builtin_amdgcn_mfma_f32_16x16x32_bf16(afrag[1][0], b0, ci, 0, 0, 0);
            a1 = __builtin_amdgcn_mfma_f32_16x16x32_bf16(afrag[1][1], b1, a1, 0, 0, 0);
            const unsigned code = codev + (unsigned)(j * 16);
            #pragma unroll
            for (int r = 0; r < 4; ++r) {
                float k0 = asf((asu(a0[r]) & 0xFFFFFC00u) | code);
                run[0][r] = fmaxf(run[0][r], k0);
                float k1 = asf((asu(a1[r]) & 0xFFFFFC00u) | code);
                run[1][r] = fmaxf(run[1][r], k1);
            }
        }
        pa += 16384; pb += 16384; pbias += 8; codev += 128;
    }

    #pragma unroll
    for (int m = 1; m <= 8; m <<= 1)
        #pragma unroll
        for (int t = 0; t < 2; ++t)
            #pragma unroll
            for (int r = 0; r < 4; ++r)
                run[t][r] = fmaxf(run[t][r], __shfl_xor(run[t][r], m, 64));

    int idxe[2];
    #pragma unroll
    for (int t = 0; t < 2; ++t) {
        const int src = (lrow >> 2) << 4;
        float g0 = __shfl(run[t][0], src, 64);
        float g1 = __shfl(run[t][1], src, 64);
        float g2 = __shfl(run[t][2], src, 64);
        float g3 = __shfl(run[t][3], src, 64);
        float sel = (lrow & 2) ? ((lrow & 1) ? g3 : g2)
                               : ((lrow & 1) ? g1 : g0);
        idxe[t] = (int)(asu(sel) & 1023u);
    }

    #pragma unroll
    for (int t = 0; t < 2; ++t) {
        const int idxr = idxe[t];
        const f32x4* ep  = (const f32x4*)(E + idxr * CDIM      + 8 * lgrp);
        const f32x4* ep2 = (const f32x4*)(E + idxr * CDIM + 32 + 8 * lgrp);
        f32x4 qa = ep[0], qb = ep[1], qc = ep2[0], qd = ep2[1];
        float* ob = outb + hw + t * 16 + lrow;
        #pragma unroll
        for (int j = 0; j < 4; ++j) {
            ob[(8 * lgrp + j)          * HWDIM] = qa[j];
            ob[(8 * lgrp + 4 + j)      * HWDIM] = qb[j];
            ob[(32 + 8 * lgrp + j)     * HWDIM] = qc[j];
            ob[(32 + 8 * lgrp + 4 + j) * HWDIM] = qd[j];
        }
    }

    float dsum = 0.f;
    #pragma unroll
    for (int t = 0; t < 2; ++t)
        #pragma unroll
        for (int r = 0; r < 4; ++r) dsum += run[t][r];
    float contrib = szz + ((lrow == 0) ? (-2.f * dsum) : 0.f);
    #pragma unroll
    for (int m = 32; m >= 1; m >>= 1) contrib += __shfl_xor(contrib, m, 64);
    if (lane == 0) partial[blockIdx.x * 16 + wave] = contrib;
}

__global__ void vq_fin(const float* __restrict__ partial,
                       float* __restrict__ out) {
    __shared__ float red[4];
    const int tid = threadIdx.x;   // 256 threads
    float s = 0.f;
    #pragma unroll
    for (int i = 0; i < NPART / 256; ++i) s += partial[i * 256 + tid];
    #pragma unroll
    for (int m = 32; m >= 1; m >>= 1) s += __shfl_xor(s, m, 64);
    if ((tid & 63) == 0) red[tid >> 6] = s;
    __syncthreads();
    if (tid == 0)
        out[NELEM] = 1.25f * (red[0] + red[1] + red[2] + red[3]) / (float)NELEM;
}

// ====================== ablation probes (write only to d_ws) ==============
// V=0 full | V=1 noDS (B preloaded once, bias=bitcast(code)) |
// V=2 noMFMA (same key-VALU on bitcast B) | V=3 noVALU (carried-acc MFMA).
// Each runs the K-sweep PASSES times to dominate the top-5 timing table.
#define PASSES 2
template<int V>
__global__ __launch_bounds__(1024)
void vq_probe(const float* __restrict__ z,
              const float* __restrict__ E,
              float* __restrict__ probeOut) {
    extern __shared__ char smem[];
    unsigned short* sEb = (unsigned short*)smem;
    float (*sBiasT)[68] = (float(*)[68])(smem + 131072);

    const int lane = threadIdx.x & 63;
    const int wave = threadIdx.x >> 6;
    const int lrow = lane & 15;
    const int lgrp = lane >> 4;

    const int n0 = blockIdx.x * 512 + wave * 32;
    const int b  = n0 >> 12;
    const int hw = n0 & 4095;
    const float* zb = z + (size_t)b * (CDIM * HWDIM);

    {   // identical fused stage
        const int t = threadIdx.x;
        const float4* ev = (const float4*)(E + t * CDIM);
        float s = 0.f;
        #pragma unroll
        for (int k = 0; k < 8; ++k) {
            float4 va = ev[2 * k], vb = ev[2 * k + 1];
            s = fmaf(va.x, va.x, s); s = fmaf(va.y, va.y, s);
            s = fmaf(va.z, va.z, s); s = fmaf(va.w, va.w, s);
            s = fmaf(vb.x, vb.x, s); s = fmaf(vb.y, vb.y, s);
            s = fmaf(vb.z, vb.z, s); s = fmaf(vb.w, vb.w, s);
            bf16x8 w;
            w[0] = (short)f2bf(va.x); w[1] = (short)f2bf(va.y);
            w[2] = (short)f2bf(va.z); w[3] = (short)f2bf(va.w);
            w[4] = (short)f2bf(vb.x); w[5] = (short)f2bf(vb.y);
            w[6] = (short)f2bf(vb.z); w[7] = (short)f2bf(vb.w);
            *(bf16x8*)((char*)sEb + t * 128 + ((k ^ (t & 7)) << 4)) = w;
        }
        sBiasT[t & 15][t >> 4] = -0.5f * s;
    }

    bf16x8 afrag[2][2];
    #pragma unroll
    for (int t = 0; t < 2; ++t)
        #pragma unroll
        for (int s = 0; s < 2; ++s)
            #pragma unroll
            for (int j = 0; j < 8; ++j) {
                int c = 32 * s + 8 * lgrp + j;
                afrag[t][s][j] = (short)f2bf(zb[c * HWDIM + hw + t * 16 + lrow]);
            }

    float run[2][4];
    #pragma unroll
    for (int t = 0; t < 2; ++t)
        #pragma unroll
        for (int r = 0; r < 4; ++r) run[t][r] = -3.0e38f;
    f32x4 acc0 = {0.f, 0.f, 0.f, 0.f}, acc1 = {0.f, 0.f, 0.f, 0.f};

    __syncthreads();

    const int s0byte = (lgrp ^ (lrow & 7)) << 4;
    const char* base_pa = (const char*)sEb + lrow * 128 + s0byte;
    const char* base_pb = (const char*)sEb + lrow * 128 + (s0byte ^ 64);

    // V=1: one-time B preload, reused (no DS in the loop)
    bf16x8 b0c = *(const bf16x8*)base_pa;
    bf16x8 b1c = *(const bf16x8*)base_pb;

    for (int pass = 0; pass < PASSES; ++pass) {
        const char* pa = base_pa;
        const char* pb = base_pb;
        const float* pbias = &sBiasT[lrow][0];
        unsigned codev = (unsigned)lrow;
        for (int ch = 0; ch < 8; ++ch) {
            f32x4 bq0 = {0.f,0.f,0.f,0.f}, bq1 = {0.f,0.f,0.f,0.f};
            if (V == 0 || V == 2) {           // bias LDS reads kept
                bq0 = *(const f32x4*)(pbias);
                bq1 = *(const f32x4*)(pbias + 4);
            }
            #pragma unroll
            for (int j = 0; j < 8; ++j) {
                const unsigned code = codev + (unsigned)(j * 16);
                bf16x8 b0, b1;
                if (V == 1) { b0 = b0c; b1 = b1c; }
                else { b0 = *(const bf16x8*)(pa + j * 2048);
                       b1 = *(const bf16x8*)(pb + j * 2048); }
                if (V == 0 || V == 1) {
                    const float bv = (V == 0) ? ((j < 4) ? bq0[j] : bq1[j - 4])
                                              : asf(code);   // kt-variant, no DS
                    f32x4 ci = {bv, bv, bv, bv};
                    f32x4 a0 = __builtin_amdgcn_mfma_f32_16x16x32_bf16(afrag[0][0], b0, ci, 0, 0, 0);
                    a0 = __builtin_amdgcn_mfma_f32_16x16x32_bf16(afrag[0][1], b1, a0, 0, 0, 0);
                    f32x4 a1 = __builtin_amdgcn_mfma_f32_16x16x32_bf16(afrag[1][0], b0, ci, 0, 0, 0);
                    a1 = __builtin_amdgcn_mfma_f32_16x16x32_bf16(afrag[1][1], b1, a1, 0, 0, 0);
                    #pragma unroll
                    for (int r = 0; r < 4; ++r) {
                        run[0][r] = fmaxf(run[0][r], asf((asu(a0[r]) & 0xFFFFFC00u) | code));
                        run[1][r] = fmaxf(run[1][r], asf((asu(a1[r]) & 0xFFFFFC00u) | code));
                    }
                } else if (V == 2) {          // same key-VALU, data from B bits
                    f32x4 x0, x1;
                    __builtin_memcpy(&x0, &b0, 16);
                    __builtin_memcpy(&x1, &b1, 16);
                    #pragma unroll
                    for (int r = 0; r < 4; ++r) {
                        run[0][r] = fmaxf(run[0][r], asf((asu(x0[r]) & 0xFFFFFC00u) | code));
                        run[1][r] = fmaxf(run[1][r], asf((asu(x1[r]) & 0xFFFFFC00u) | code));
                    }
                } else {                      // V == 3: MFMA only, carried acc
                    acc0 = __builtin_amdgcn_mfma_f32_16x16x32_bf16(afrag[0][0], b0, acc0, 0, 0, 0);
                    acc0 = __builtin_amdgcn_mfma_f32_16x16x32_bf16(afrag[0][1], b1, acc0, 0, 0, 0);
                    acc1 = __builtin_amdgcn_mfma_f32_16x16x32_bf16(afrag[1][0], b0, acc1, 0, 0, 0);
                    acc1 = __builtin_amdgcn_mfma_f32_16x16x32_bf16(afrag[1][1], b1, acc1, 0, 0, 0);
                }
            }
            pa += 16384; pb += 16384; pbias += 8; codev += 128;
        }
    }

    // keep everything live; one store per wave
    float c2 = 0.f;
    #pragma unroll
    for (int t = 0; t < 2; ++t)
        #pragma unroll
        for (int r = 0; r < 4; ++r) c2 += run[t][r];
    #pragma unroll
    for (int r = 0; r < 4; ++r) c2 += acc0[r] + acc1[r];
    #pragma unroll
    for (int m = 32; m >= 1; m >>= 1) c2 += __shfl_xor(c2, m, 64);
    if (lane == 0) probeOut[blockIdx.x * 16 + wave] = c2;
}

extern "C" void kernel_launch(void* const* d_in, const int* in_sizes, int n_in,
                              void* d_out, int out_size, void* d_ws, size_t ws_size,
                              hipStream_t stream) {
    const float* z = (const float*)d_in[0];
    const float* E = (const float*)d_in[1];
    float* out = (float*)d_out;
    float* partial = (float*)d_ws;                          // 16 KB
    float* probeA  = (float*)((char*)d_ws + 16384);         // 16 KB
    float* probeB  = (float*)((char*)d_ws + 32768);
    float* probeC  = (float*)((char*)d_ws + 49152);
    float* probeD  = (float*)((char*)d_ws + 65536);

    hipFuncSetAttribute((const void*)vq_main,
                        hipFuncAttributeMaxDynamicSharedMemorySize, LDSSZ);
    hipFuncSetAttribute((const void*)vq_probe<0>,
                        hipFuncAttributeMaxDynamicSharedMemorySize, LDSSZ);
    hipFuncSetAttribute((const void*)vq_probe<1>,
                        hipFuncAttributeMaxDynamicSharedMemorySize, LDSSZ);
    hipFuncSetAttribute((const void*)vq_probe<2>,
                        hipFuncAttributeMaxDynamicSharedMemorySize, LDSSZ);
    hipFuncSetAttribute((const void*)vq_probe<3>,
                        hipFuncAttributeMaxDynamicSharedMemorySize, LDSSZ);

    vq_main<<<NBLOCK, 1024, LDSSZ, stream>>>(z, E, out, partial);
    vq_fin<<<1, 256, 0, stream>>>(partial, out);
    // ---- ablation probes (scratch-only writes; timing info via rocprof) ----
    vq_probe<0><<<NBLOCK, 1024, LDSSZ, stream>>>(z, E, probeA);
    vq_probe<1><<<NBLOCK, 1024, LDSSZ, stream>>>(z, E, probeB);
    vq_probe<2><<<NBLOCK, 1024, LDSSZ, stream>>>(z, E, probeC);
    vq_probe<3><<<NBLOCK, 1024, LDSSZ, stream>>>(z, E, probeD);
}

// Round 15
// 130.704 us; speedup vs baseline: 2.5497x; 2.5497x over previous
//
#include <hip/hip_runtime.h>
#include <hip/hip_bf16.h>

#define CDIM   64
#define HWDIM  4096
#define NCODES 1024
#define NELEM  8388608   // 32*64*64*64 = N*C
#define NBLOCK 256       // one block per CU, 512 rows each
#define NPART  (NBLOCK * 16)
#define LDSSZ  (131072 + 16 * 68 * 4)   // 128 KB codebook + padded bias

typedef short bf16x8 __attribute__((ext_vector_type(8)));
typedef float f32x4  __attribute__((ext_vector_type(4)));

__device__ __forceinline__ unsigned short f2bf(float f) {
    union { float f; unsigned u; } v; v.f = f;
    unsigned r = v.u + 0x7fffu + ((v.u >> 16) & 1u);
    return (unsigned short)(r >> 16);
}
__device__ __forceinline__ unsigned asu(float f) {
    union { float f; unsigned u; } v; v.f = f; return v.u;
}
__device__ __forceinline__ float asf(unsigned u) {
    union { unsigned u; float f; } v; v.u = u; return v.f;
}

// ====================== real kernel (R13, unchanged) ======================
__global__ __launch_bounds__(1024)
void vq_main(const float* __restrict__ z,
             const float* __restrict__ E,
             float* __restrict__ out,
             float* __restrict__ partial) {
    extern __shared__ char smem[];
    unsigned short* sEb = (unsigned short*)smem;
    float (*sBiasT)[68] = (float(*)[68])(smem + 131072);

    const int lane = threadIdx.x & 63;
    const int wave = threadIdx.x >> 6;
    const int lrow = lane & 15;
    const int lgrp = lane >> 4;

    const int n0 = blockIdx.x * 512 + wave * 32;
    const int b  = n0 >> 12;
    const int hw = n0 & 4095;
    const float* zb   = z   + (size_t)b * (CDIM * HWDIM);
    float*       outb = out + (size_t)b * (CDIM * HWDIM);

    {   // fused prep+stage
        const int t = threadIdx.x;
        const float4* ev = (const float4*)(E + t * CDIM);
        float s = 0.f;
        #pragma unroll
        for (int k = 0; k < 8; ++k) {
            float4 va = ev[2 * k], vb = ev[2 * k + 1];
            s = fmaf(va.x, va.x, s); s = fmaf(va.y, va.y, s);
            s = fmaf(va.z, va.z, s); s = fmaf(va.w, va.w, s);
            s = fmaf(vb.x, vb.x, s); s = fmaf(vb.y, vb.y, s);
            s = fmaf(vb.z, vb.z, s); s = fmaf(vb.w, vb.w, s);
            bf16x8 w;
            w[0] = (short)f2bf(va.x); w[1] = (short)f2bf(va.y);
            w[2] = (short)f2bf(va.z); w[3] = (short)f2bf(va.w);
            w[4] = (short)f2bf(vb.x); w[5] = (short)f2bf(vb.y);
            w[6] = (short)f2bf(vb.z); w[7] = (short)f2bf(vb.w);
            *(bf16x8*)((char*)sEb + t * 128 + ((k ^ (t & 7)) << 4)) = w;
        }
        sBiasT[t & 15][t >> 4] = -0.5f * s;
    }

    float szz = 0.f;
    bf16x8 afrag[2][2];
    #pragma unroll
    for (int t = 0; t < 2; ++t)
        #pragma unroll
        for (int s = 0; s < 2; ++s)
            #pragma unroll
            for (int j = 0; j < 8; ++j) {
                int c = 32 * s + 8 * lgrp + j;
                float v = zb[c * HWDIM + hw + t * 16 + lrow];
                szz = fmaf(v, v, szz);
                afrag[t][s][j] = (short)f2bf(v);
            }

    float run[2][4];
    #pragma unroll
    for (int t = 0; t < 2; ++t)
        #pragma unroll
        for (int r = 0; r < 4; ++r) run[t][r] = -3.0e38f;

    __syncthreads();

    const int s0byte = (lgrp ^ (lrow & 7)) << 4;
    const char* pa = (const char*)sEb + lrow * 128 + s0byte;
    const char* pb = (const char*)sEb + lrow * 128 + (s0byte ^ 64);
    const float* pbias = &sBiasT[lrow][0];
    unsigned codev = (unsigned)lrow;

    for (int ch = 0; ch < 8; ++ch) {
        f32x4 bq0 = *(const f32x4*)(pbias);
        f32x4 bq1 = *(const f32x4*)(pbias + 4);
        #pragma unroll
        for (int j = 0; j < 8; ++j) {
            bf16x8 b0 = *(const bf16x8*)(pa + j * 2048);
            bf16x8 b1 = *(const bf16x8*)(pb + j * 2048);
            const float bv = (j < 4) ? bq0[j] : bq1[j - 4];
            f32x4 ci = {bv, bv, bv, bv};
            f32x4 a0 = __builtin_amdgcn_mfma_f32_16x16x32_bf16(afrag[0][0], b0, ci, 0, 0, 0);
            a0 = __builtin_amdgcn_mfma_f32_16x16x32_bf16(afrag[0][1], b1, a0, 0, 0, 0);
            f32x4 a1 = __builtin_amdgcn_mfma_f32_16x16x32_bf16(afrag[1][0], b0, ci, 0, 0, 0);
            a1 = __builtin_amdgcn_mfma_f32_16x16x32_bf16(afrag[1][1], b1, a1, 0, 0, 0);
            const unsigned code = codev + (unsigned)(j * 16);
            #pragma unroll
            for (int r = 0; r < 4; ++r) {
                float k0 = asf((asu(a0[r]) & 0xFFFFFC00u) | code);
                run[0][r] = fmaxf(run[0][r], k0);
                float k1 = asf((asu(a1[r]) & 0xFFFFFC00u) | code);
                run[1][r] = fmaxf(run[1][r], k1);
            }
        }
        pa += 16384; pb += 16384; pbias += 8; codev += 128;
    }

    #pragma unroll
    for (int m = 1; m <= 8; m <<= 1)
        #pragma unroll
        for (int t = 0; t < 2; ++t)
            #pragma unroll
            for (int r = 0; r < 4; ++r)
                run[t][r] = fmaxf(run[t][r], __shfl_xor(run[t][r], m, 64));

    int idxe[2];
    #pragma unroll
    for (int t = 0; t < 2; ++t) {
        const int src = (lrow >> 2) << 4;
        float g0 = __shfl(run[t][0], src, 64);
        float g1 = __shfl(run[t][1], src, 64);
        float g2 = __shfl(run[t][2], src, 64);
        float g3 = __shfl(run[t][3], src, 64);
        float sel = (lrow & 2) ? ((lrow & 1) ? g3 : g2)
                               : ((lrow & 1) ? g1 : g0);
        idxe[t] = (int)(asu(sel) & 1023u);
    }

    #pragma unroll
    for (int t = 0; t < 2; ++t) {
        const int idxr = idxe[t];
        const f32x4* ep  = (const f32x4*)(E + idxr * CDIM      + 8 * lgrp);
        const f32x4* ep2 = (const f32x4*)(E + idxr * CDIM + 32 + 8 * lgrp);
        f32x4 qa = ep[0], qb = ep[1], qc = ep2[0], qd = ep2[1];
        float* ob = outb + hw + t * 16 + lrow;
        #pragma unroll
        for (int j = 0; j < 4; ++j) {
            ob[(8 * lgrp + j)          * HWDIM] = qa[j];
            ob[(8 * lgrp + 4 + j)      * HWDIM] = qb[j];
            ob[(32 + 8 * lgrp + j)     * HWDIM] = qc[j];
            ob[(32 + 8 * lgrp + 4 + j) * HWDIM] = qd[j];
        }
    }

    float dsum = 0.f;
    #pragma unroll
    for (int t = 0; t < 2; ++t)
        #pragma unroll
        for (int r = 0; r < 4; ++r) dsum += run[t][r];
    float contrib = szz + ((lrow == 0) ? (-2.f * dsum) : 0.f);
    #pragma unroll
    for (int m = 32; m >= 1; m >>= 1) contrib += __shfl_xor(contrib, m, 64);
    if (lane == 0) partial[blockIdx.x * 16 + wave] = contrib;
}

__global__ void vq_fin(const float* __restrict__ partial,
                       float* __restrict__ out) {
    __shared__ float red[4];
    const int tid = threadIdx.x;
    float s = 0.f;
    #pragma unroll
    for (int i = 0; i < NPART / 256; ++i) s += partial[i * 256 + tid];
    #pragma unroll
    for (int m = 32; m >= 1; m >>= 1) s += __shfl_xor(s, m, 64);
    if ((tid & 63) == 0) red[tid >> 6] = s;
    __syncthreads();
    if (tid == 0)
        out[NELEM] = 1.25f * (red[0] + red[1] + red[2] + red[3]) / (float)NELEM;
}

// ====================== lean ablation probes ==============================
// V=0 full K-loop | V=1 noKey (carried-acc MFMA) | V=2 noDS (preloaded B,
// bias=asf(code)) | V=3 noMFMA (keys on B bits) | V=4 prologue only.
// Each variant declares ONLY its own state (R14 spill lesson); afrag kept
// live where unused via asm keep-alive (rule #17). Single pass.
template<int V>
__global__ __launch_bounds__(1024)
void vq_probe(const float* __restrict__ z,
              const float* __restrict__ E,
              float* __restrict__ probeOut) {
    extern __shared__ char smem[];
    unsigned short* sEb = (unsigned short*)smem;
    float (*sBiasT)[68] = (float(*)[68])(smem + 131072);

    const int lane = threadIdx.x & 63;
    const int wave = threadIdx.x >> 6;
    const int lrow = lane & 15;
    const int lgrp = lane >> 4;

    const int n0 = blockIdx.x * 512 + wave * 32;
    const int b  = n0 >> 12;
    const int hw = n0 & 4095;
    const float* zb = z + (size_t)b * (CDIM * HWDIM);

    {   // identical fused stage
        const int t = threadIdx.x;
        const float4* ev = (const float4*)(E + t * CDIM);
        float s = 0.f;
        #pragma unroll
        for (int k = 0; k < 8; ++k) {
            float4 va = ev[2 * k], vb = ev[2 * k + 1];
            s = fmaf(va.x, va.x, s); s = fmaf(va.y, va.y, s);
            s = fmaf(va.z, va.z, s); s = fmaf(va.w, va.w, s);
            s = fmaf(vb.x, vb.x, s); s = fmaf(vb.y, vb.y, s);
            s = fmaf(vb.z, vb.z, s); s = fmaf(vb.w, vb.w, s);
            bf16x8 w;
            w[0] = (short)f2bf(va.x); w[1] = (short)f2bf(va.y);
            w[2] = (short)f2bf(va.z); w[3] = (short)f2bf(va.w);
            w[4] = (short)f2bf(vb.x); w[5] = (short)f2bf(vb.y);
            w[6] = (short)f2bf(vb.z); w[7] = (short)f2bf(vb.w);
            *(bf16x8*)((char*)sEb + t * 128 + ((k ^ (t & 7)) << 4)) = w;
        }
        sBiasT[t & 15][t >> 4] = -0.5f * s;
    }

    // A-load (always executed; kept live via fold + asm when unused)
    bf16x8 afrag[2][2];
    #pragma unroll
    for (int t = 0; t < 2; ++t)
        #pragma unroll
        for (int s = 0; s < 2; ++s)
            #pragma unroll
            for (int j = 0; j < 8; ++j) {
                int c = 32 * s + 8 * lgrp + j;
                afrag[t][s][j] = (short)f2bf(zb[c * HWDIM + hw + t * 16 + lrow]);
            }
    if constexpr (V == 3 || V == 4) {
        int dummy = 0;
        #pragma unroll
        for (int t = 0; t < 2; ++t)
            #pragma unroll
            for (int s = 0; s < 2; ++s)
                dummy ^= ((const int*)&afrag[t][s])[0] ^ ((const int*)&afrag[t][s])[3];
        asm volatile("" :: "v"(dummy));   // keep A-load without keeping afrag
    }

    __syncthreads();

    if constexpr (V == 4) {   // prologue-only floor
        if (lane == 0) probeOut[blockIdx.x * 16 + wave] = 1.0f;
        return;
    } else {
        const int s0byte = (lgrp ^ (lrow & 7)) << 4;
        const char* pa = (const char*)sEb + lrow * 128 + s0byte;
        const char* pb = (const char*)sEb + lrow * 128 + (s0byte ^ 64);
        const float* pbias = &sBiasT[lrow][0];
        unsigned codev = (unsigned)lrow;

        float run[2][4];
        #pragma unroll
        for (int t = 0; t < 2; ++t)
            #pragma unroll
            for (int r = 0; r < 4; ++r) run[t][r] = -3.0e38f;
        f32x4 acc0 = {0.f,0.f,0.f,0.f}, acc1 = {0.f,0.f,0.f,0.f};
        bf16x8 b0c, b1c;
        if constexpr (V == 2) { b0c = *(const bf16x8*)pa; b1c = *(const bf16x8*)pb; }

        for (int ch = 0; ch < 8; ++ch) {
            f32x4 bq0, bq1;
            if constexpr (V == 0 || V == 3) {
                bq0 = *(const f32x4*)(pbias);
                bq1 = *(const f32x4*)(pbias + 4);
            }
            #pragma unroll
            for (int j = 0; j < 8; ++j) {
                const unsigned code = codev + (unsigned)(j * 16);
                if constexpr (V == 0) {
                    bf16x8 b0 = *(const bf16x8*)(pa + j * 2048);
                    bf16x8 b1 = *(const bf16x8*)(pb + j * 2048);
                    const float bv = (j < 4) ? bq0[j] : bq1[j - 4];
                    f32x4 ci = {bv, bv, bv, bv};
                    f32x4 a0 = __builtin_amdgcn_mfma_f32_16x16x32_bf16(afrag[0][0], b0, ci, 0, 0, 0);
                    a0 = __builtin_amdgcn_mfma_f32_16x16x32_bf16(afrag[0][1], b1, a0, 0, 0, 0);
                    f32x4 a1 = __builtin_amdgcn_mfma_f32_16x16x32_bf16(afrag[1][0], b0, ci, 0, 0, 0);
                    a1 = __builtin_amdgcn_mfma_f32_16x16x32_bf16(afrag[1][1], b1, a1, 0, 0, 0);
                    #pragma unroll
                    for (int r = 0; r < 4; ++r) {
                        run[0][r] = fmaxf(run[0][r], asf((asu(a0[r]) & 0xFFFFFC00u) | code));
                        run[1][r] = fmaxf(run[1][r], asf((asu(a1[r]) & 0xFFFFFC00u) | code));
                    }
                } else if constexpr (V == 1) {   // noKey: ds + carried-acc MFMA
                    bf16x8 b0 = *(const bf16x8*)(pa + j * 2048);
                    bf16x8 b1 = *(const bf16x8*)(pb + j * 2048);
                    acc0 = __builtin_amdgcn_mfma_f32_16x16x32_bf16(afrag[0][0], b0, acc0, 0, 0, 0);
                    acc0 = __builtin_amdgcn_mfma_f32_16x16x32_bf16(afrag[0][1], b1, acc0, 0, 0, 0);
                    acc1 = __builtin_amdgcn_mfma_f32_16x16x32_bf16(afrag[1][0], b0, acc1, 0, 0, 0);
                    acc1 = __builtin_amdgcn_mfma_f32_16x16x32_bf16(afrag[1][1], b1, acc1, 0, 0, 0);
                } else if constexpr (V == 2) {   // noDS: preloaded B + keys
                    const float bv = asf(code);
                    f32x4 ci = {bv, bv, bv, bv};
                    f32x4 a0 = __builtin_amdgcn_mfma_f32_16x16x32_bf16(afrag[0][0], b0c, ci, 0, 0, 0);
                    a0 = __builtin_amdgcn_mfma_f32_16x16x32_bf16(afrag[0][1], b1c, a0, 0, 0, 0);
                    f32x4 a1 = __builtin_amdgcn_mfma_f32_16x16x32_bf16(afrag[1][0], b0c, ci, 0, 0, 0);
                    a1 = __builtin_amdgcn_mfma_f32_16x16x32_bf16(afrag[1][1], b1c, a1, 0, 0, 0);
                    #pragma unroll
                    for (int r = 0; r < 4; ++r) {
                        run[0][r] = fmaxf(run[0][r], asf((asu(a0[r]) & 0xFFFFFC00u) | code));
                        run[1][r] = fmaxf(run[1][r], asf((asu(a1[r]) & 0xFFFFFC00u) | code));
                    }
                } else {                          // V == 3: noMFMA, keys on B bits
                    bf16x8 b0 = *(const bf16x8*)(pa + j * 2048);
                    bf16x8 b1 = *(const bf16x8*)(pb + j * 2048);
                    f32x4 x0, x1;
                    __builtin_memcpy(&x0, &b0, 16);
                    __builtin_memcpy(&x1, &b1, 16);
                    const float bv = (j < 4) ? bq0[j] : bq1[j - 4];
                    #pragma unroll
                    for (int r = 0; r < 4; ++r) {
                        run[0][r] = fmaxf(run[0][r], asf((asu(x0[r] + bv) & 0xFFFFFC00u) | code));
                        run[1][r] = fmaxf(run[1][r], asf((asu(x1[r] + bv) & 0xFFFFFC00u) | code));
                    }
                }
            }
            pa += 16384; pb += 16384; pbias += 8; codev += 128;
        }

        float s = 0.f;
        if constexpr (V == 1) {
            #pragma unroll
            for (int r = 0; r < 4; ++r) s += acc0[r] + acc1[r];
        } else {
            #pragma unroll
            for (int t = 0; t < 2; ++t)
                #pragma unroll
                for (int r = 0; r < 4; ++r) s += run[t][r];
        }
        #pragma unroll
        for (int m = 32; m >= 1; m >>= 1) s += __shfl_xor(s, m, 64);
        if (lane == 0) probeOut[blockIdx.x * 16 + wave] = s;
    }
}

extern "C" void kernel_launch(void* const* d_in, const int* in_sizes, int n_in,
                              void* d_out, int out_size, void* d_ws, size_t ws_size,
                              hipStream_t stream) {
    const float* z = (const float*)d_in[0];
    const float* E = (const float*)d_in[1];
    float* out = (float*)d_out;
    float* partial = (float*)d_ws;                      // 16 KB
    float* probeBuf = (float*)((char*)d_ws + 16384);    // 5 x 16 KB

    hipFuncSetAttribute((const void*)vq_main,
                        hipFuncAttributeMaxDynamicSharedMemorySize, LDSSZ);
    hipFuncSetAttribute((const void*)vq_probe<0>,
                        hipFuncAttributeMaxDynamicSharedMemorySize, LDSSZ);
    hipFuncSetAttribute((const void*)vq_probe<1>,
                        hipFuncAttributeMaxDynamicSharedMemorySize, LDSSZ);
    hipFuncSetAttribute((const void*)vq_probe<2>,
                        hipFuncAttributeMaxDynamicSharedMemorySize, LDSSZ);
    hipFuncSetAttribute((const void*)vq_probe<3>,
                        hipFuncAttributeMaxDynamicSharedMemorySize, LDSSZ);
    hipFuncSetAttribute((const void*)vq_probe<4>,
                        hipFuncAttributeMaxDynamicSharedMemorySize, LDSSZ);

    vq_main<<<NBLOCK, 1024, LDSSZ, stream>>>(z, E, out, partial);
    vq_fin<<<1, 256, 0, stream>>>(partial, out);
    // ---- ablation probes (scratch-only; timed via rocprof dispatches) ----
    vq_probe<0><<<NBLOCK, 1024, LDSSZ, stream>>>(z, E, probeBuf);
    vq_probe<1><<<NBLOCK, 1024, LDSSZ, stream>>>(z, E, probeBuf + 4096);
    vq_probe<2><<<NBLOCK, 1024, LDSSZ, stream>>>(z, E, probeBuf + 8192);
    vq_probe<3><<<NBLOCK, 1024, LDSSZ, stream>>>(z, E, probeBuf + 12288);
    vq_probe<4><<<NBLOCK, 1024, LDSSZ, stream>>>(z, E, probeBuf + 16384);
}

// Round 16
// 37.242 us; speedup vs baseline: 8.9482x; 3.5095x over previous
//
#include <hip/hip_runtime.h>
#include <hip/hip_bf16.h>

#define CDIM   64
#define HWDIM  4096
#define NCODES 1024
#define NELEM  8388608   // 32*64*64*64 = N*C
#define NBLOCK 256       // one block per CU, 512 rows each
#define NPART  (NBLOCK * 16)
#define LDSSZ  (131072 + 16 * 68 * 4)   // 128 KB codebook + padded bias

typedef short bf16x8 __attribute__((ext_vector_type(8)));
typedef float f32x4  __attribute__((ext_vector_type(4)));

__device__ __forceinline__ unsigned short f2bf(float f) {
    union { float f; unsigned u; } v; v.f = f;
    unsigned r = v.u + 0x7fffu + ((v.u >> 16) & 1u);   // round-to-nearest-even
    return (unsigned short)(r >> 16);
}
__device__ __forceinline__ unsigned asu(float f) {
    union { float f; unsigned u; } v; v.f = f; return v.u;
}
__device__ __forceinline__ float asf(unsigned u) {
    union { unsigned u; float f; } v; v.u = u; return v.f;
}

// One block per CU (1024 thr = 16 waves x 32 rows). Fused prep+stage: fp32 E
// -> bf16 swizzled LDS codebook + transposed bias; ONE barrier; LDS-only
// K-loop with fully hoisted addressing (ds_read_b128, immediate offsets);
// packed-key argmax (code idx in low 10 mantissa bits). Epilogue gathers q
// from the LDS bf16 codebook (bf16->f32 via <<16; err ~2e-6 << 2.5e-2) —
// no global E-gather. __launch_bounds__(1024,4): 16 waves = 4 waves/EU
// exactly -> VGPR cap 128 (was 64), zero occupancy cost since 128 KB LDS
// already limits to 1 block/CU. (R7/R12/R14 lesson: never request an
// occupancy the register file can't fund — this one it can.)
__global__ __launch_bounds__(1024, 4)
void vq_main(const float* __restrict__ z,
             const float* __restrict__ E,
             float* __restrict__ out,
             float* __restrict__ partial) {
    extern __shared__ char smem[];
    unsigned short* sEb = (unsigned short*)smem;           // 128 KB swizzled
    float (*sBiasT)[68] = (float(*)[68])(smem + 131072);   // [16][68] padded

    const int lane = threadIdx.x & 63;
    const int wave = threadIdx.x >> 6;   // 0..15
    const int lrow = lane & 15;          // row/code-col within 16-tile
    const int lgrp = lane >> 4;          // k-group 0..3

    const int n0 = blockIdx.x * 512 + wave * 32;  // wave's first flat row
    const int b  = n0 >> 12;
    const int hw = n0 & 4095;
    const float* zb   = z   + (size_t)b * (CDIM * HWDIM);
    float*       outb = out + (size_t)b * (CDIM * HWDIM);

    {   // fused prep+stage: thread t owns code t (exactly 1024 threads)
        const int t = threadIdx.x;
        const float4* ev = (const float4*)(E + t * CDIM);
        float s = 0.f;
        #pragma unroll
        for (int k = 0; k < 8; ++k) {
            float4 va = ev[2 * k], vb = ev[2 * k + 1];
            s = fmaf(va.x, va.x, s); s = fmaf(va.y, va.y, s);
            s = fmaf(va.z, va.z, s); s = fmaf(va.w, va.w, s);
            s = fmaf(vb.x, vb.x, s); s = fmaf(vb.y, vb.y, s);
            s = fmaf(vb.z, vb.z, s); s = fmaf(vb.w, vb.w, s);
            bf16x8 w;
            w[0] = (short)f2bf(va.x); w[1] = (short)f2bf(va.y);
            w[2] = (short)f2bf(va.z); w[3] = (short)f2bf(va.w);
            w[4] = (short)f2bf(vb.x); w[5] = (short)f2bf(vb.y);
            w[6] = (short)f2bf(vb.z); w[7] = (short)f2bf(vb.w);
            *(bf16x8*)((char*)sEb + t * 128 + ((k ^ (t & 7)) << 4)) = w;
        }
        sBiasT[t & 15][t >> 4] = -0.5f * s;
    }

    // A fragments: tile t rows n0+16t..+15. lane holds A[lrow][k=32s+8g+j].
    float szz = 0.f;
    bf16x8 afrag[2][2];
    #pragma unroll
    for (int t = 0; t < 2; ++t)
        #pragma unroll
        for (int s = 0; s < 2; ++s)
            #pragma unroll
            for (int j = 0; j < 8; ++j) {
                int c = 32 * s + 8 * lgrp + j;
                float v = zb[c * HWDIM + hw + t * 16 + lrow];
                szz = fmaf(v, v, szz);
                afrag[t][s][j] = (short)f2bf(v);
            }

    float run[2][4];
    #pragma unroll
    for (int t = 0; t < 2; ++t)
        #pragma unroll
        for (int r = 0; r < 4; ++r) run[t][r] = -3.0e38f;

    __syncthreads();   // the ONLY barrier: staged codebook + bias complete

    // loop-invariant swizzled addresses (rowh&7 == lrow&7 for all kt)
    const int s0byte = (lgrp ^ (lrow & 7)) << 4;
    const char* pa = (const char*)sEb + lrow * 128 + s0byte;
    const char* pb = (const char*)sEb + lrow * 128 + (s0byte ^ 64);
    const float* pbias = &sBiasT[lrow][0];
    unsigned codev = (unsigned)lrow;

    for (int ch = 0; ch < 8; ++ch) {
        f32x4 bq0 = *(const f32x4*)(pbias);       // biases kt = ch*8+0..3
        f32x4 bq1 = *(const f32x4*)(pbias + 4);   // biases kt = ch*8+4..7
        #pragma unroll
        for (int j = 0; j < 8; ++j) {
            bf16x8 b0 = *(const bf16x8*)(pa + j * 2048);
            bf16x8 b1 = *(const bf16x8*)(pb + j * 2048);
            const float bv = (j < 4) ? bq0[j] : bq1[j - 4];   // static idx
            f32x4 ci = {bv, bv, bv, bv};
            f32x4 a0 = __builtin_amdgcn_mfma_f32_16x16x32_bf16(afrag[0][0], b0, ci, 0, 0, 0);
            a0 = __builtin_amdgcn_mfma_f32_16x16x32_bf16(afrag[0][1], b1, a0, 0, 0, 0);
            f32x4 a1 = __builtin_amdgcn_mfma_f32_16x16x32_bf16(afrag[1][0], b0, ci, 0, 0, 0);
            a1 = __builtin_amdgcn_mfma_f32_16x16x32_bf16(afrag[1][1], b1, a1, 0, 0, 0);
            const unsigned code = codev + (unsigned)(j * 16);
            #pragma unroll
            for (int r = 0; r < 4; ++r) {
                float k0 = asf((asu(a0[r]) & 0xFFFFFC00u) | code);
                run[0][r] = fmaxf(run[0][r], k0);
                float k1 = asf((asu(a1[r]) & 0xFFFFFC00u) | code);
                run[1][r] = fmaxf(run[1][r], k1);
            }
        }
        pa += 16384; pb += 16384; pbias += 8; codev += 128;
    }

    // reduce packed keys across the 16 code-columns (lrow lanes): pure max
    #pragma unroll
    for (int m = 1; m <= 8; m <<= 1)
        #pragma unroll
        for (int t = 0; t < 2; ++t)
            #pragma unroll
            for (int r = 0; r < 4; ++r)
                run[t][r] = fmaxf(run[t][r], __shfl_xor(run[t][r], m, 64));

    // redistribute winners via shuffles: lane (lrow,lgrp) holds rows 4g+r;
    // epilogue thread needs row lrow of each tile.
    int idxe[2];
    #pragma unroll
    for (int t = 0; t < 2; ++t) {
        const int src = (lrow >> 2) << 4;   // a lane whose lgrp == lrow>>2
        float g0 = __shfl(run[t][0], src, 64);
        float g1 = __shfl(run[t][1], src, 64);
        float g2 = __shfl(run[t][2], src, 64);
        float g3 = __shfl(run[t][3], src, 64);
        float sel = (lrow & 2) ? ((lrow & 1) ? g3 : g2)
                               : ((lrow & 1) ? g1 : g0);
        idxe[t] = (int)(asu(sel) & 1023u);
    }

    // epilogue: gather q from the LDS bf16 codebook (swizzled), cvt via <<16,
    // write transposed out. No global E access.
    #pragma unroll
    for (int t = 0; t < 2; ++t) {
        const int idxr = idxe[t];
        const int off0 = (lgrp ^ (idxr & 7)) << 4;        // chunk lgrp
        const char* qp = (const char*)sEb + idxr * 128;
        bf16x8 q0 = *(const bf16x8*)(qp + off0);           // c = 8g..8g+7
        bf16x8 q1 = *(const bf16x8*)(qp + (off0 ^ 64));    // c = 32+8g..+7
        float* ob = outb + hw + t * 16 + lrow;
        #pragma unroll
        for (int j = 0; j < 8; ++j) {
            ob[(8 * lgrp + j)      * HWDIM] = asf(((unsigned)(unsigned short)q0[j]) << 16);
            ob[(32 + 8 * lgrp + j) * HWDIM] = asf(((unsigned)(unsigned short)q1[j]) << 16);
        }
    }

    // loss partial: sum z^2 + sum over rows of d_min (= -2 * packed score)
    float dsum = 0.f;
    #pragma unroll
    for (int t = 0; t < 2; ++t)
        #pragma unroll
        for (int r = 0; r < 4; ++r) dsum += run[t][r];
    float contrib = szz + ((lrow == 0) ? (-2.f * dsum) : 0.f);
    #pragma unroll
    for (int m = 32; m >= 1; m >>= 1) contrib += __shfl_xor(contrib, m, 64);
    if (lane == 0) partial[blockIdx.x * 16 + wave] = contrib;
}

__global__ void vq_fin(const float* __restrict__ partial,
                       float* __restrict__ out) {
    __shared__ float red[4];
    const int tid = threadIdx.x;   // 256 threads
    float s = 0.f;
    #pragma unroll
    for (int i = 0; i < NPART / 256; ++i) s += partial[i * 256 + tid];
    #pragma unroll
    for (int m = 32; m >= 1; m >>= 1) s += __shfl_xor(s, m, 64);
    if ((tid & 63) == 0) red[tid >> 6] = s;
    __syncthreads();
    if (tid == 0)
        out[NELEM] = 1.25f * (red[0] + red[1] + red[2] + red[3]) / (float)NELEM;
}

extern "C" void kernel_launch(void* const* d_in, const int* in_sizes, int n_in,
                              void* d_out, int out_size, void* d_ws, size_t ws_size,
                              hipStream_t stream) {
    const float* z = (const float*)d_in[0];
    const float* E = (const float*)d_in[1];
    float* out = (float*)d_out;
    float* partial = (float*)d_ws;   // 16 KB

    // allow >64 KB dynamic LDS (host-side attribute; graph-capture safe)
    hipFuncSetAttribute((const void*)vq_main,
                        hipFuncAttributeMaxDynamicSharedMemorySize, LDSSZ);

    vq_main<<<NBLOCK, 1024, LDSSZ, stream>>>(z, E, out, partial);
    vq_fin<<<1, 256, 0, stream>>>(partial, out);
}